// Round 5
// baseline (231.357 us; speedup 1.0000x reference)
//
#include <hip/hip_runtime.h>
#include <hip/hip_bf16.h>

#define N_NODES 50000
#define N_EDGES 800000
#define IN_DIM 128
#define HIDDEN 128
#define OUT_DIM 40
#define G_STRIDE 64                                       // padded g row (128B line)

#define SCAN_BS 1024
#define SCAN_BLOCKS ((N_NODES + SCAN_BS - 1) / SCAN_BS)   // 49

#define N_BUCKETS 8
#define HIST_STRIDE 50176                                 // line-aligned copy stride

#define HIST_BLOCKS 3128                                  // covers 800768 slots (guarded)
#define G1_BLOCKS ((N_NODES + 63) / 64)                   // 782
#define HG_GRID 3910                                      // 782 gemm1 (bid%5==4) + 3128 hist

struct __align__(8) Edge { int s; float w; };

typedef __attribute__((ext_vector_type(8))) short bf16x8;   // MFMA A/B frag (4 VGPR)
typedef __attribute__((ext_vector_type(4))) float f32x4;    // MFMA C/D frag

// fp32 -> bf16 bits with round-to-nearest-even
__device__ __forceinline__ unsigned f32_to_bf16_bits(float f) {
    unsigned u = __float_as_uint(f);
    return (u + 0x7FFFu + ((u >> 16) & 1u)) >> 16;
}

// ---- 1) fused hist + gemm1, INTERLEAVED 1:4. copy = blockIdx&7 so all
// atomics to one hist copy come from blocks on ONE XCD (round-robin
// dispatch): lines stay in that XCD's L2 slice instead of bouncing.
__global__ __launch_bounds__(256) void hist_gemm1(const int* __restrict__ dst,
                                                  int* __restrict__ hist8,
                                                  unsigned short* __restrict__ erank,
                                                  const float* __restrict__ x,
                                                  const float* __restrict__ W1,
                                                  __hip_bfloat16* __restrict__ y)
{
    __shared__ bf16x8 w1s[2048];                  // 32 KB (gemm1 blocks only)
    int bid = blockIdx.x;

    if ((bid % 5) != 4) {
        // -------- hist path --------
        int hb = bid - bid / 5;                   // 0..3127
        int i = hb * 256 + threadIdx.x;
        if (i < N_EDGES) {
            int copy = bid & (N_BUCKETS - 1);     // physical-XCD-aligned
            erank[i] = (unsigned short)atomicAdd(&hist8[copy * HIST_STRIDE + dst[i]], 1);
        }
        return;
    }

    // -------- gemm1 path: y = x @ W1 (v_mfma_f32_16x16x32_bf16) --------
    int gb = bid / 5;                             // 0..781
    int t = threadIdx.x;
    for (int f = t; f < 2048; f += 256) {         // 8 frags per thread
        int lane = f & 63;
        int nt = (f >> 6) & 7;
        int ks = f >> 9;
        int m = lane & 15, quad = lane >> 4;
        bf16x8 frag;
        #pragma unroll
        for (int j = 0; j < 8; ++j) {
            int k = ks * 32 + quad * 8 + j;
            frag[j] = (short)f32_to_bf16_bits(W1[k * HIDDEN + nt * 16 + m]);
        }
        w1s[f] = frag;
    }
    __syncthreads();

    int wv = t >> 6;
    int lane = t & 63;
    int m = lane & 15, quad = lane >> 4;
    int row0 = gb * 64 + wv * 16;
    int arow = row0 + m;
    if (arow >= N_NODES) arow = N_NODES - 1;      // clamp loads; stores guarded

    bf16x8 afrag[4];
    #pragma unroll
    for (int ks = 0; ks < 4; ++ks) {
        const float4* xp = (const float4*)(x + (long long)arow * IN_DIM + ks * 32 + quad * 8);
        float4 a0 = xp[0], a1 = xp[1];
        afrag[ks][0] = (short)f32_to_bf16_bits(a0.x);
        afrag[ks][1] = (short)f32_to_bf16_bits(a0.y);
        afrag[ks][2] = (short)f32_to_bf16_bits(a0.z);
        afrag[ks][3] = (short)f32_to_bf16_bits(a0.w);
        afrag[ks][4] = (short)f32_to_bf16_bits(a1.x);
        afrag[ks][5] = (short)f32_to_bf16_bits(a1.y);
        afrag[ks][6] = (short)f32_to_bf16_bits(a1.z);
        afrag[ks][7] = (short)f32_to_bf16_bits(a1.w);
    }

    f32x4 acc[8];
    #pragma unroll
    for (int nt = 0; nt < 8; ++nt) acc[nt] = (f32x4){0.f, 0.f, 0.f, 0.f};

    #pragma unroll
    for (int ks = 0; ks < 4; ++ks) {
        #pragma unroll
        for (int nt = 0; nt < 8; ++nt) {
            bf16x8 bfrag = w1s[(ks * 8 + nt) * 64 + lane];
            acc[nt] = __builtin_amdgcn_mfma_f32_16x16x32_bf16(afrag[ks], bfrag, acc[nt], 0, 0, 0);
        }
    }

    #pragma unroll
    for (int nt = 0; nt < 8; ++nt) {
        #pragma unroll
        for (int r = 0; r < 4; ++r) {
            int rrow = row0 + quad * 4 + r;
            if (rrow < N_NODES)
                y[(long long)rrow * HIDDEN + nt * 16 + m] = __float2bfloat16(acc[nt][r]);
        }
    }
}

// ---- 2a) convert 8 copies -> per-copy exclusive offsets (in place),
// total into cnt, plus per-block partial sums for the scan ----------------
__global__ __launch_bounds__(SCAN_BS) void scan_partial(int* __restrict__ hist8,
                                                        int* __restrict__ cnt,
                                                        int* __restrict__ block_sums)
{
    __shared__ int red[SCAN_BS / 64];
    int i = blockIdx.x * SCAN_BS + threadIdx.x;
    int total = 0;
    if (i < N_NODES) {
        int off = 0;
        #pragma unroll
        for (int c = 0; c < N_BUCKETS; ++c) {
            int h = hist8[c * HIST_STRIDE + i];
            hist8[c * HIST_STRIDE + i] = off;     // exclusive prefix over copies
            off += h;
        }
        total = off;
        cnt[i] = total;
    }
    int s = total;
    for (int off = 32; off > 0; off >>= 1) s += __shfl_down(s, off, 64);
    int wave = threadIdx.x >> 6, lane = threadIdx.x & 63;
    if (lane == 0) red[wave] = s;
    __syncthreads();
    if (threadIdx.x == 0) {
        int tt = 0;
        #pragma unroll
        for (int wv = 0; wv < SCAN_BS / 64; ++wv) tt += red[wv];
        block_sums[blockIdx.x] = tt;
    }
}

// ---- 2b) block-local exclusive scan; PARALLEL prefix over block_sums
// (one 64-lane load + shuffle reduce instead of thread-0 serial walk) ------
__global__ __launch_bounds__(SCAN_BS) void scan_final(const int* __restrict__ cnt,
                                                      const int* __restrict__ block_sums,
                                                      int* __restrict__ row_ptr)
{
    __shared__ int tmp[SCAN_BS];
    __shared__ int blk_off;
    int t = threadIdx.x;
    int i = blockIdx.x * SCAN_BS + t;
    if (t < 64) {                                  // SCAN_BLOCKS=49 <= 64 lanes
        int v2 = (t < (int)blockIdx.x) ? block_sums[t] : 0;
        for (int off = 32; off > 0; off >>= 1) v2 += __shfl_down(v2, off, 64);
        if (t == 0) {
            blk_off = v2;
            if (blockIdx.x == 0) row_ptr[N_NODES] = N_EDGES;
        }
    }
    int v = (i < N_NODES) ? cnt[i] : 0;
    tmp[t] = v;
    __syncthreads();
    for (int off = 1; off < SCAN_BS; off <<= 1) {
        int u = (t >= off) ? tmp[t - off] : 0;
        __syncthreads();
        tmp[t] += u;
        __syncthreads();
    }
    if (i < N_NODES) row_ptr[i] = tmp[t] - v + blk_off;
}

// ---- 3) scatter_det: SINGLE-PASS deterministic placement, NO atomics.
// copy(i) recomputed via the hist renumbering inverse: hb=i>>8, bid=hb+hb/4.
__global__ __launch_bounds__(256) void scatter_det(const int* __restrict__ src,
                                                   const int* __restrict__ dst,
                                                   const float* __restrict__ w,
                                                   const int* __restrict__ hist8,
                                                   const unsigned short* __restrict__ erank,
                                                   const int* __restrict__ row_ptr,
                                                   Edge* __restrict__ edges)
{
    int i = blockIdx.x * 256 + threadIdx.x;       // grid exact: 3125*256
    int d = dst[i];
    int hb = i >> 8;
    int hbid = hb + (hb >> 2);                    // inverse of hb = bid - bid/5
    int copy = hbid & (N_BUCKETS - 1);            // == hist's bid&7
    int pos = row_ptr[d] + hist8[copy * HIST_STRIDE + d] + (int)erank[i];
    Edge ed; ed.s = src[i]; ed.w = w[i];
    edges[pos] = ed;
}

// ---- 4) spmm1: h1 = relu(A @ y + b1); wave/node, 8-deep gather unroll -----
__global__ __launch_bounds__(256) void spmm1_kernel(const int* __restrict__ row_ptr,
                                                    const Edge* __restrict__ edges,
                                                    const __hip_bfloat16* __restrict__ y,
                                                    const float* __restrict__ b1,
                                                    __hip_bfloat16* __restrict__ h1)
{
    int node = blockIdx.x * 4 + (threadIdx.x >> 6);
    int lane = threadIdx.x & 63;
    if (node >= N_NODES) return;
    int beg = row_ptr[node];
    int end = row_ptr[node + 1];
    const __hip_bfloat162* yv = (const __hip_bfloat162*)y;
    float ax = 0.f, ay = 0.f;
    int j = beg;
    for (; j + 7 < end; j += 8) {                 // 8 gathers in flight
        Edge e0 = edges[j + 0];
        Edge e1 = edges[j + 1];
        Edge e2 = edges[j + 2];
        Edge e3 = edges[j + 3];
        Edge e4 = edges[j + 4];
        Edge e5 = edges[j + 5];
        Edge e6 = edges[j + 6];
        Edge e7 = edges[j + 7];
        __hip_bfloat162 v0 = yv[(e0.s << 6) + lane];
        __hip_bfloat162 v1 = yv[(e1.s << 6) + lane];
        __hip_bfloat162 v2 = yv[(e2.s << 6) + lane];
        __hip_bfloat162 v3 = yv[(e3.s << 6) + lane];
        __hip_bfloat162 v4 = yv[(e4.s << 6) + lane];
        __hip_bfloat162 v5 = yv[(e5.s << 6) + lane];
        __hip_bfloat162 v6 = yv[(e6.s << 6) + lane];
        __hip_bfloat162 v7 = yv[(e7.s << 6) + lane];
        ax = fmaf(e0.w, __low2float(v0), ax);  ay = fmaf(e0.w, __high2float(v0), ay);
        ax = fmaf(e1.w, __low2float(v1), ax);  ay = fmaf(e1.w, __high2float(v1), ay);
        ax = fmaf(e2.w, __low2float(v2), ax);  ay = fmaf(e2.w, __high2float(v2), ay);
        ax = fmaf(e3.w, __low2float(v3), ax);  ay = fmaf(e3.w, __high2float(v3), ay);
        ax = fmaf(e4.w, __low2float(v4), ax);  ay = fmaf(e4.w, __high2float(v4), ay);
        ax = fmaf(e5.w, __low2float(v5), ax);  ay = fmaf(e5.w, __high2float(v5), ay);
        ax = fmaf(e6.w, __low2float(v6), ax);  ay = fmaf(e6.w, __high2float(v6), ay);
        ax = fmaf(e7.w, __low2float(v7), ax);  ay = fmaf(e7.w, __high2float(v7), ay);
    }
    for (; j + 3 < end; j += 4) {
        Edge e0 = edges[j + 0];
        Edge e1 = edges[j + 1];
        Edge e2 = edges[j + 2];
        Edge e3 = edges[j + 3];
        __hip_bfloat162 v0 = yv[(e0.s << 6) + lane];
        __hip_bfloat162 v1 = yv[(e1.s << 6) + lane];
        __hip_bfloat162 v2 = yv[(e2.s << 6) + lane];
        __hip_bfloat162 v3 = yv[(e3.s << 6) + lane];
        ax = fmaf(e0.w, __low2float(v0), ax);  ay = fmaf(e0.w, __high2float(v0), ay);
        ax = fmaf(e1.w, __low2float(v1), ax);  ay = fmaf(e1.w, __high2float(v1), ay);
        ax = fmaf(e2.w, __low2float(v2), ax);  ay = fmaf(e2.w, __high2float(v2), ay);
        ax = fmaf(e3.w, __low2float(v3), ax);  ay = fmaf(e3.w, __high2float(v3), ay);
    }
    for (; j < end; ++j) {
        Edge e0 = edges[j];
        __hip_bfloat162 v0 = yv[(e0.s << 6) + lane];
        ax = fmaf(e0.w, __low2float(v0), ax);
        ay = fmaf(e0.w, __high2float(v0), ay);
    }
    float2 bv = ((const float2*)b1)[lane];
    __hip_bfloat162 hv;
    hv.x = __float2bfloat16(fmaxf(ax + bv.x, 0.f));
    hv.y = __float2bfloat16(fmaxf(ay + bv.y, 0.f));
    ((__hip_bfloat162*)h1)[(node << 6) + lane] = hv;
}

// ---- 5) gemm2: g = h1 @ W2; 8 rows/block amortize the W2 pass -------------
#define G2_ROWS 8
__global__ __launch_bounds__(64) void gemm2_kernel(const __hip_bfloat16* __restrict__ h1,
                                                   const float* __restrict__ W2,
                                                   __hip_bfloat16* __restrict__ g)
{
    __shared__ float xs[G2_ROWS][HIDDEN];
    int row0 = blockIdx.x * G2_ROWS;
    int t = threadIdx.x;
    #pragma unroll
    for (int r = 0; r < G2_ROWS; ++r) {
        xs[r][t]      = __bfloat162float(h1[(long long)(row0 + r) * HIDDEN + t]);
        xs[r][t + 64] = __bfloat162float(h1[(long long)(row0 + r) * HIDDEN + t + 64]);
    }
    __syncthreads();
    if (t >= OUT_DIM) return;
    float acc[G2_ROWS];
    #pragma unroll
    for (int r = 0; r < G2_ROWS; ++r) acc[r] = 0.f;
    #pragma unroll 4
    for (int k = 0; k < HIDDEN; ++k) {
        float wv = W2[k * OUT_DIM + t];
        #pragma unroll
        for (int r = 0; r < G2_ROWS; ++r)
            acc[r] = fmaf(xs[r][k], wv, acc[r]);
    }
    #pragma unroll
    for (int r = 0; r < G2_ROWS; ++r)
        g[((row0 + r) << 6) + t] = __float2bfloat16(acc[r]);   // padded row
}

// ---- 6) spmm2: out = A @ g + b2; wave/node, 40 active lanes; g row is one
// aligned 128B line per edge gather; 8-deep gather unroll ------------------
__global__ __launch_bounds__(256) void spmm2_kernel(const int* __restrict__ row_ptr,
                                                    const Edge* __restrict__ edges,
                                                    const __hip_bfloat16* __restrict__ g,
                                                    const float* __restrict__ b2,
                                                    float* __restrict__ out)
{
    int node = blockIdx.x * 4 + (threadIdx.x >> 6);
    int lane = threadIdx.x & 63;
    if (node >= N_NODES) return;
    if (lane >= OUT_DIM) return;
    int beg = row_ptr[node];
    int end = row_ptr[node + 1];
    float acc = 0.f;
    int j = beg;
    for (; j + 7 < end; j += 8) {
        Edge e0 = edges[j + 0];
        Edge e1 = edges[j + 1];
        Edge e2 = edges[j + 2];
        Edge e3 = edges[j + 3];
        Edge e4 = edges[j + 4];
        Edge e5 = edges[j + 5];
        Edge e6 = edges[j + 6];
        Edge e7 = edges[j + 7];
        float v0 = __bfloat162float(g[(e0.s << 6) + lane]);
        float v1 = __bfloat162float(g[(e1.s << 6) + lane]);
        float v2 = __bfloat162float(g[(e2.s << 6) + lane]);
        float v3 = __bfloat162float(g[(e3.s << 6) + lane]);
        float v4 = __bfloat162float(g[(e4.s << 6) + lane]);
        float v5 = __bfloat162float(g[(e5.s << 6) + lane]);
        float v6 = __bfloat162float(g[(e6.s << 6) + lane]);
        float v7 = __bfloat162float(g[(e7.s << 6) + lane]);
        acc = fmaf(e0.w, v0, acc);
        acc = fmaf(e1.w, v1, acc);
        acc = fmaf(e2.w, v2, acc);
        acc = fmaf(e3.w, v3, acc);
        acc = fmaf(e4.w, v4, acc);
        acc = fmaf(e5.w, v5, acc);
        acc = fmaf(e6.w, v6, acc);
        acc = fmaf(e7.w, v7, acc);
    }
    for (; j + 3 < end; j += 4) {
        Edge e0 = edges[j + 0];
        Edge e1 = edges[j + 1];
        Edge e2 = edges[j + 2];
        Edge e3 = edges[j + 3];
        float v0 = __bfloat162float(g[(e0.s << 6) + lane]);
        float v1 = __bfloat162float(g[(e1.s << 6) + lane]);
        float v2 = __bfloat162float(g[(e2.s << 6) + lane]);
        float v3 = __bfloat162float(g[(e3.s << 6) + lane]);
        acc = fmaf(e0.w, v0, acc);
        acc = fmaf(e1.w, v1, acc);
        acc = fmaf(e2.w, v2, acc);
        acc = fmaf(e3.w, v3, acc);
    }
    for (; j < end; ++j) {
        Edge e0 = edges[j];
        acc = fmaf(e0.w, __bfloat162float(g[(e0.s << 6) + lane]), acc);
    }
    out[(long long)node * OUT_DIM + lane] = acc + b2[lane];
}

extern "C" void kernel_launch(void* const* d_in, const int* in_sizes, int n_in,
                              void* d_out, int out_size, void* d_ws, size_t ws_size,
                              hipStream_t stream)
{
    const float* x    = (const float*)d_in[0];
    const int*   esrc = (const int*)  d_in[1];
    const int*   edst = (const int*)  d_in[2];
    const float* ew   = (const float*)d_in[3];
    const float* W1   = (const float*)d_in[4];
    const float* b1   = (const float*)d_in[5];
    const float* W2   = (const float*)d_in[6];
    const float* b2   = (const float*)d_in[7];
    float* out = (float*)d_out;

    // workspace layout (~36 MB); g aliases y (y is dead after spmm1)
    __hip_bfloat16* y  = (__hip_bfloat16*)d_ws;                  // 12.8 MB
    __hip_bfloat16* g  = y;                                      // 6.4 MB (aliased)
    __hip_bfloat16* h1 = y + (size_t)N_NODES * HIDDEN;           // 12.8 MB
    Edge* edges     = (Edge*)(h1 + (size_t)N_NODES * HIDDEN);    // 6.4 MB
    int* hist8      = (int*)(edges + N_EDGES);                   // 1.6 MB
    unsigned short* erank = (unsigned short*)(hist8 + N_BUCKETS * HIST_STRIDE); // 1.6 MB
    int* cnt        = (int*)(erank + N_EDGES);                   // 200 KB
    int* row_ptr    = cnt + 50176;                               // 50001 (pad 50176)
    int* block_sums = row_ptr + 50176;                           // 64 ints

    // CSR build + gemm1 co-run (interleaved 1:4 so MFMA overlaps atomics)
    hipMemsetAsync(hist8, 0, N_BUCKETS * HIST_STRIDE * sizeof(int), stream);
    hist_gemm1<<<HG_GRID, 256, 0, stream>>>(edst, hist8, erank, x, W1, y);
    scan_partial<<<SCAN_BLOCKS, SCAN_BS, 0, stream>>>(hist8, cnt, block_sums);
    scan_final<<<SCAN_BLOCKS, SCAN_BS, 0, stream>>>(cnt, block_sums, row_ptr);
    scatter_det<<<N_EDGES / 256, 256, 0, stream>>>(esrc, edst, ew, hist8,
                                                   erank, row_ptr, edges);

    // h1 = relu(A @ y + b1)
    spmm1_kernel<<<N_NODES / 4, 256, 0, stream>>>(row_ptr, edges, y, b1, h1);
    // g = h1 @ W2 (8-row W2 amortization; padded g rows)
    gemm2_kernel<<<N_NODES / G2_ROWS, 64, 0, stream>>>(h1, W2, g);
    // out = A @ g + b2
    spmm2_kernel<<<(N_NODES + 3) / 4, 256, 0, stream>>>(row_ptr, edges, g, b2, out);
}

// Round 6
// 228.522 us; speedup vs baseline: 1.0124x; 1.0124x over previous
//
#include <hip/hip_runtime.h>
#include <hip/hip_bf16.h>

#define N_NODES 50000
#define N_EDGES 800000
#define IN_DIM 128
#define HIDDEN 128
#define OUT_DIM 40
#define G_STRIDE 64                                       // padded g row (128B line)

#define SCAN_BS 1024
#define SCAN_BLOCKS ((N_NODES + SCAN_BS - 1) / SCAN_BS)   // 49

#define N_COPIES 32                                       // hist copies (line-contention relief)
#define HIST_STRIDE 50176                                 // line-aligned copy stride

#define HIST_BLOCKS 3128                                  // covers 800768 slots (guarded)
#define G1_BLOCKS ((N_NODES + 63) / 64)                   // 782
#define HG_GRID 3910                                      // 782 gemm1 (bid%5==4) + 3128 hist

struct __align__(8) Edge { int s; float w; };

typedef __attribute__((ext_vector_type(8))) short bf16x8;   // MFMA A/B frag (4 VGPR)
typedef __attribute__((ext_vector_type(4))) float f32x4;    // MFMA C/D frag

// fp32 -> bf16 bits with round-to-nearest-even
__device__ __forceinline__ unsigned f32_to_bf16_bits(float f) {
    unsigned u = __float_as_uint(f);
    return (u + 0x7FFFu + ((u >> 16) & 1u)) >> 16;
}

// ---- 1) fused hist + gemm1, INTERLEAVED 1:4. 32 hist copies: atomics
// write through L2 to the memory-side cache (round-5 null proved XCD
// alignment irrelevant); contention is per-LINE serialization, so 4x more
// lines = 4x less serialization.
__global__ __launch_bounds__(256) void hist_gemm1(const int* __restrict__ dst,
                                                  int* __restrict__ hist8,
                                                  unsigned short* __restrict__ erank,
                                                  const float* __restrict__ x,
                                                  const float* __restrict__ W1,
                                                  __hip_bfloat16* __restrict__ y)
{
    __shared__ bf16x8 w1s[2048];                  // 32 KB (gemm1 blocks only)
    int bid = blockIdx.x;

    if ((bid % 5) != 4) {
        // -------- hist path --------
        int hb = bid - bid / 5;                   // 0..3127
        int i = hb * 256 + threadIdx.x;
        if (i < N_EDGES) {
            int copy = bid & (N_COPIES - 1);
            erank[i] = (unsigned short)atomicAdd(&hist8[copy * HIST_STRIDE + dst[i]], 1);
        }
        return;
    }

    // -------- gemm1 path: y = x @ W1 (v_mfma_f32_16x16x32_bf16) --------
    int gb = bid / 5;                             // 0..781
    int t = threadIdx.x;
    for (int f = t; f < 2048; f += 256) {         // 8 frags per thread
        int lane = f & 63;
        int nt = (f >> 6) & 7;
        int ks = f >> 9;
        int m = lane & 15, quad = lane >> 4;
        bf16x8 frag;
        #pragma unroll
        for (int j = 0; j < 8; ++j) {
            int k = ks * 32 + quad * 8 + j;
            frag[j] = (short)f32_to_bf16_bits(W1[k * HIDDEN + nt * 16 + m]);
        }
        w1s[f] = frag;
    }
    __syncthreads();

    int wv = t >> 6;
    int lane = t & 63;
    int m = lane & 15, quad = lane >> 4;
    int row0 = gb * 64 + wv * 16;
    int arow = row0 + m;
    if (arow >= N_NODES) arow = N_NODES - 1;      // clamp loads; stores guarded

    bf16x8 afrag[4];
    #pragma unroll
    for (int ks = 0; ks < 4; ++ks) {
        const float4* xp = (const float4*)(x + (long long)arow * IN_DIM + ks * 32 + quad * 8);
        float4 a0 = xp[0], a1 = xp[1];
        afrag[ks][0] = (short)f32_to_bf16_bits(a0.x);
        afrag[ks][1] = (short)f32_to_bf16_bits(a0.y);
        afrag[ks][2] = (short)f32_to_bf16_bits(a0.z);
        afrag[ks][3] = (short)f32_to_bf16_bits(a0.w);
        afrag[ks][4] = (short)f32_to_bf16_bits(a1.x);
        afrag[ks][5] = (short)f32_to_bf16_bits(a1.y);
        afrag[ks][6] = (short)f32_to_bf16_bits(a1.z);
        afrag[ks][7] = (short)f32_to_bf16_bits(a1.w);
    }

    f32x4 acc[8];
    #pragma unroll
    for (int nt = 0; nt < 8; ++nt) acc[nt] = (f32x4){0.f, 0.f, 0.f, 0.f};

    #pragma unroll
    for (int ks = 0; ks < 4; ++ks) {
        #pragma unroll
        for (int nt = 0; nt < 8; ++nt) {
            bf16x8 bfrag = w1s[(ks * 8 + nt) * 64 + lane];
            acc[nt] = __builtin_amdgcn_mfma_f32_16x16x32_bf16(afrag[ks], bfrag, acc[nt], 0, 0, 0);
        }
    }

    #pragma unroll
    for (int nt = 0; nt < 8; ++nt) {
        #pragma unroll
        for (int r = 0; r < 4; ++r) {
            int rrow = row0 + quad * 4 + r;
            if (rrow < N_NODES)
                y[(long long)rrow * HIDDEN + nt * 16 + m] = __float2bfloat16(acc[nt][r]);
        }
    }
}

// ---- 2a) convert 32 copies -> per-copy exclusive offsets (in place),
// total into cnt, plus per-block partial sums for the scan ----------------
__global__ __launch_bounds__(SCAN_BS) void scan_partial(int* __restrict__ hist8,
                                                        int* __restrict__ cnt,
                                                        int* __restrict__ block_sums)
{
    __shared__ int red[SCAN_BS / 64];
    int i = blockIdx.x * SCAN_BS + threadIdx.x;
    int total = 0;
    if (i < N_NODES) {
        int off = 0;
        #pragma unroll
        for (int c = 0; c < N_COPIES; ++c) {
            int h = hist8[c * HIST_STRIDE + i];
            hist8[c * HIST_STRIDE + i] = off;     // exclusive prefix over copies
            off += h;
        }
        total = off;
        cnt[i] = total;
    }
    int s = total;
    for (int off = 32; off > 0; off >>= 1) s += __shfl_down(s, off, 64);
    int wave = threadIdx.x >> 6, lane = threadIdx.x & 63;
    if (lane == 0) red[wave] = s;
    __syncthreads();
    if (threadIdx.x == 0) {
        int tt = 0;
        #pragma unroll
        for (int wv = 0; wv < SCAN_BS / 64; ++wv) tt += red[wv];
        block_sums[blockIdx.x] = tt;
    }
}

// ---- 2b) block-local exclusive scan; PARALLEL prefix over block_sums -----
__global__ __launch_bounds__(SCAN_BS) void scan_final(const int* __restrict__ cnt,
                                                      const int* __restrict__ block_sums,
                                                      int* __restrict__ row_ptr)
{
    __shared__ int tmp[SCAN_BS];
    __shared__ int blk_off;
    int t = threadIdx.x;
    int i = blockIdx.x * SCAN_BS + t;
    if (t < 64) {                                  // SCAN_BLOCKS=49 <= 64 lanes
        int v2 = (t < (int)blockIdx.x) ? block_sums[t] : 0;
        for (int off = 32; off > 0; off >>= 1) v2 += __shfl_down(v2, off, 64);
        if (t == 0) {
            blk_off = v2;
            if (blockIdx.x == 0) row_ptr[N_NODES] = N_EDGES;
        }
    }
    int v = (i < N_NODES) ? cnt[i] : 0;
    tmp[t] = v;
    __syncthreads();
    for (int off = 1; off < SCAN_BS; off <<= 1) {
        int u = (t >= off) ? tmp[t - off] : 0;
        __syncthreads();
        tmp[t] += u;
        __syncthreads();
    }
    if (i < N_NODES) row_ptr[i] = tmp[t] - v + blk_off;
}

// ---- 3) scatter_det: SINGLE-PASS deterministic placement, NO atomics.
// copy(i) recomputed via the hist renumbering inverse: hb=i>>8, bid=hb+hb/4.
__global__ __launch_bounds__(256) void scatter_det(const int* __restrict__ src,
                                                   const int* __restrict__ dst,
                                                   const float* __restrict__ w,
                                                   const int* __restrict__ hist8,
                                                   const unsigned short* __restrict__ erank,
                                                   const int* __restrict__ row_ptr,
                                                   Edge* __restrict__ edges)
{
    int i = blockIdx.x * 256 + threadIdx.x;       // grid exact: 3125*256
    int d = dst[i];
    int hb = i >> 8;
    int hbid = hb + (hb >> 2);                    // inverse of hb = bid - bid/5
    int copy = hbid & (N_COPIES - 1);             // == hist's bid&31
    int pos = row_ptr[d] + hist8[copy * HIST_STRIDE + d] + (int)erank[i];
    Edge ed; ed.s = src[i]; ed.w = w[i];
    edges[pos] = ed;
}

// ---- 4) spmm1: h1 = relu(A @ y + b1). DUAL-NODE waves: each wave owns 2
// nodes with independent 8-deep gather chains -> 16 gathers + 16 edge loads
// in flight per wave (2x MLP vs single-node unroll-8).
__global__ __launch_bounds__(256) void spmm1_kernel(const int* __restrict__ row_ptr,
                                                    const Edge* __restrict__ edges,
                                                    const __hip_bfloat16* __restrict__ y,
                                                    const float* __restrict__ b1,
                                                    __hip_bfloat16* __restrict__ h1)
{
    int wv = threadIdx.x >> 6;
    int lane = threadIdx.x & 63;
    int nA = blockIdx.x * 8 + wv * 2;             // grid exact: 6250*8 = 50000
    int nB = nA + 1;
    int jA = row_ptr[nA], eA = row_ptr[nA + 1];
    int jB = row_ptr[nB], eB = row_ptr[nB + 1];
    const __hip_bfloat162* yv = (const __hip_bfloat162*)y;
    float axA = 0.f, ayA = 0.f, axB = 0.f, ayB = 0.f;

    while (jA + 7 < eA && jB + 7 < eB) {          // dual 8-deep chains
        Edge ea[8], eb[8];
        #pragma unroll
        for (int u = 0; u < 8; ++u) ea[u] = edges[jA + u];
        #pragma unroll
        for (int u = 0; u < 8; ++u) eb[u] = edges[jB + u];
        __hip_bfloat162 va[8], vb[8];
        #pragma unroll
        for (int u = 0; u < 8; ++u) va[u] = yv[(ea[u].s << 6) + lane];
        #pragma unroll
        for (int u = 0; u < 8; ++u) vb[u] = yv[(eb[u].s << 6) + lane];
        #pragma unroll
        for (int u = 0; u < 8; ++u) {
            axA = fmaf(ea[u].w, __low2float(va[u]), axA);
            ayA = fmaf(ea[u].w, __high2float(va[u]), ayA);
            axB = fmaf(eb[u].w, __low2float(vb[u]), axB);
            ayB = fmaf(eb[u].w, __high2float(vb[u]), ayB);
        }
        jA += 8; jB += 8;
    }
    // drain A
    for (; jA + 7 < eA; jA += 8) {
        Edge ea[8];
        #pragma unroll
        for (int u = 0; u < 8; ++u) ea[u] = edges[jA + u];
        __hip_bfloat162 va[8];
        #pragma unroll
        for (int u = 0; u < 8; ++u) va[u] = yv[(ea[u].s << 6) + lane];
        #pragma unroll
        for (int u = 0; u < 8; ++u) {
            axA = fmaf(ea[u].w, __low2float(va[u]), axA);
            ayA = fmaf(ea[u].w, __high2float(va[u]), ayA);
        }
    }
    for (; jA + 3 < eA; jA += 4) {
        Edge ea[4];
        #pragma unroll
        for (int u = 0; u < 4; ++u) ea[u] = edges[jA + u];
        __hip_bfloat162 va[4];
        #pragma unroll
        for (int u = 0; u < 4; ++u) va[u] = yv[(ea[u].s << 6) + lane];
        #pragma unroll
        for (int u = 0; u < 4; ++u) {
            axA = fmaf(ea[u].w, __low2float(va[u]), axA);
            ayA = fmaf(ea[u].w, __high2float(va[u]), ayA);
        }
    }
    for (; jA < eA; ++jA) {
        Edge e0 = edges[jA];
        __hip_bfloat162 v0 = yv[(e0.s << 6) + lane];
        axA = fmaf(e0.w, __low2float(v0), axA);
        ayA = fmaf(e0.w, __high2float(v0), ayA);
    }
    // drain B
    for (; jB + 7 < eB; jB += 8) {
        Edge eb[8];
        #pragma unroll
        for (int u = 0; u < 8; ++u) eb[u] = edges[jB + u];
        __hip_bfloat162 vb[8];
        #pragma unroll
        for (int u = 0; u < 8; ++u) vb[u] = yv[(eb[u].s << 6) + lane];
        #pragma unroll
        for (int u = 0; u < 8; ++u) {
            axB = fmaf(eb[u].w, __low2float(vb[u]), axB);
            ayB = fmaf(eb[u].w, __high2float(vb[u]), ayB);
        }
    }
    for (; jB + 3 < eB; jB += 4) {
        Edge eb[4];
        #pragma unroll
        for (int u = 0; u < 4; ++u) eb[u] = edges[jB + u];
        __hip_bfloat162 vb[4];
        #pragma unroll
        for (int u = 0; u < 4; ++u) vb[u] = yv[(eb[u].s << 6) + lane];
        #pragma unroll
        for (int u = 0; u < 4; ++u) {
            axB = fmaf(eb[u].w, __low2float(vb[u]), axB);
            ayB = fmaf(eb[u].w, __high2float(vb[u]), ayB);
        }
    }
    for (; jB < eB; ++jB) {
        Edge e0 = edges[jB];
        __hip_bfloat162 v0 = yv[(e0.s << 6) + lane];
        axB = fmaf(e0.w, __low2float(v0), axB);
        ayB = fmaf(e0.w, __high2float(v0), ayB);
    }

    float2 bv = ((const float2*)b1)[lane];
    __hip_bfloat162 hA, hB;
    hA.x = __float2bfloat16(fmaxf(axA + bv.x, 0.f));
    hA.y = __float2bfloat16(fmaxf(ayA + bv.y, 0.f));
    hB.x = __float2bfloat16(fmaxf(axB + bv.x, 0.f));
    hB.y = __float2bfloat16(fmaxf(ayB + bv.y, 0.f));
    ((__hip_bfloat162*)h1)[(nA << 6) + lane] = hA;
    ((__hip_bfloat162*)h1)[(nB << 6) + lane] = hB;
}

// ---- 5) gemm2: g = h1 @ W2; 8 rows/block amortize the W2 pass -------------
#define G2_ROWS 8
__global__ __launch_bounds__(64) void gemm2_kernel(const __hip_bfloat16* __restrict__ h1,
                                                   const float* __restrict__ W2,
                                                   __hip_bfloat16* __restrict__ g)
{
    __shared__ float xs[G2_ROWS][HIDDEN];
    int row0 = blockIdx.x * G2_ROWS;
    int t = threadIdx.x;
    #pragma unroll
    for (int r = 0; r < G2_ROWS; ++r) {
        xs[r][t]      = __bfloat162float(h1[(long long)(row0 + r) * HIDDEN + t]);
        xs[r][t + 64] = __bfloat162float(h1[(long long)(row0 + r) * HIDDEN + t + 64]);
    }
    __syncthreads();
    if (t >= OUT_DIM) return;
    float acc[G2_ROWS];
    #pragma unroll
    for (int r = 0; r < G2_ROWS; ++r) acc[r] = 0.f;
    #pragma unroll 4
    for (int k = 0; k < HIDDEN; ++k) {
        float wv = W2[k * OUT_DIM + t];
        #pragma unroll
        for (int r = 0; r < G2_ROWS; ++r)
            acc[r] = fmaf(xs[r][k], wv, acc[r]);
    }
    #pragma unroll
    for (int r = 0; r < G2_ROWS; ++r)
        g[((row0 + r) << 6) + t] = __float2bfloat16(acc[r]);   // padded row
}

// ---- 6) spmm2: out = A @ g + b2. DUAL-NODE waves, 40 active lanes,
// aligned 128B-line gathers (padded g rows) --------------------------------
__global__ __launch_bounds__(256) void spmm2_kernel(const int* __restrict__ row_ptr,
                                                    const Edge* __restrict__ edges,
                                                    const __hip_bfloat16* __restrict__ g,
                                                    const float* __restrict__ b2,
                                                    float* __restrict__ out)
{
    int wv = threadIdx.x >> 6;
    int lane = threadIdx.x & 63;
    if (lane >= OUT_DIM) return;
    int nA = blockIdx.x * 8 + wv * 2;             // grid exact: 6250*8 = 50000
    int nB = nA + 1;
    int jA = row_ptr[nA], eA = row_ptr[nA + 1];
    int jB = row_ptr[nB], eB = row_ptr[nB + 1];
    float accA = 0.f, accB = 0.f;

    while (jA + 7 < eA && jB + 7 < eB) {
        Edge ea[8], eb[8];
        #pragma unroll
        for (int u = 0; u < 8; ++u) ea[u] = edges[jA + u];
        #pragma unroll
        for (int u = 0; u < 8; ++u) eb[u] = edges[jB + u];
        float va[8], vb[8];
        #pragma unroll
        for (int u = 0; u < 8; ++u) va[u] = __bfloat162float(g[(ea[u].s << 6) + lane]);
        #pragma unroll
        for (int u = 0; u < 8; ++u) vb[u] = __bfloat162float(g[(eb[u].s << 6) + lane]);
        #pragma unroll
        for (int u = 0; u < 8; ++u) {
            accA = fmaf(ea[u].w, va[u], accA);
            accB = fmaf(eb[u].w, vb[u], accB);
        }
        jA += 8; jB += 8;
    }
    for (; jA + 7 < eA; jA += 8) {
        Edge ea[8];
        #pragma unroll
        for (int u = 0; u < 8; ++u) ea[u] = edges[jA + u];
        float va[8];
        #pragma unroll
        for (int u = 0; u < 8; ++u) va[u] = __bfloat162float(g[(ea[u].s << 6) + lane]);
        #pragma unroll
        for (int u = 0; u < 8; ++u) accA = fmaf(ea[u].w, va[u], accA);
    }
    for (; jA + 3 < eA; jA += 4) {
        Edge ea[4];
        #pragma unroll
        for (int u = 0; u < 4; ++u) ea[u] = edges[jA + u];
        float va[4];
        #pragma unroll
        for (int u = 0; u < 4; ++u) va[u] = __bfloat162float(g[(ea[u].s << 6) + lane]);
        #pragma unroll
        for (int u = 0; u < 4; ++u) accA = fmaf(ea[u].w, va[u], accA);
    }
    for (; jA < eA; ++jA) {
        Edge e0 = edges[jA];
        accA = fmaf(e0.w, __bfloat162float(g[(e0.s << 6) + lane]), accA);
    }
    for (; jB + 7 < eB; jB += 8) {
        Edge eb[8];
        #pragma unroll
        for (int u = 0; u < 8; ++u) eb[u] = edges[jB + u];
        float vb[8];
        #pragma unroll
        for (int u = 0; u < 8; ++u) vb[u] = __bfloat162float(g[(eb[u].s << 6) + lane]);
        #pragma unroll
        for (int u = 0; u < 8; ++u) accB = fmaf(eb[u].w, vb[u], accB);
    }
    for (; jB + 3 < eB; jB += 4) {
        Edge eb[4];
        #pragma unroll
        for (int u = 0; u < 4; ++u) eb[u] = edges[jB + u];
        float vb[4];
        #pragma unroll
        for (int u = 0; u < 4; ++u) vb[u] = __bfloat162float(g[(eb[u].s << 6) + lane]);
        #pragma unroll
        for (int u = 0; u < 4; ++u) accB = fmaf(eb[u].w, vb[u], accB);
    }
    for (; jB < eB; ++jB) {
        Edge e0 = edges[jB];
        accB = fmaf(e0.w, __bfloat162float(g[(e0.s << 6) + lane]), accB);
    }

    float bb = b2[lane];
    out[(long long)nA * OUT_DIM + lane] = accA + bb;
    out[(long long)nB * OUT_DIM + lane] = accB + bb;
}

extern "C" void kernel_launch(void* const* d_in, const int* in_sizes, int n_in,
                              void* d_out, int out_size, void* d_ws, size_t ws_size,
                              hipStream_t stream)
{
    const float* x    = (const float*)d_in[0];
    const int*   esrc = (const int*)  d_in[1];
    const int*   edst = (const int*)  d_in[2];
    const float* ew   = (const float*)d_in[3];
    const float* W1   = (const float*)d_in[4];
    const float* b1   = (const float*)d_in[5];
    const float* W2   = (const float*)d_in[6];
    const float* b2   = (const float*)d_in[7];
    float* out = (float*)d_out;

    // workspace layout (~41 MB); g aliases y (y is dead after spmm1)
    __hip_bfloat16* y  = (__hip_bfloat16*)d_ws;                  // 12.8 MB
    __hip_bfloat16* g  = y;                                      // 6.4 MB (aliased)
    __hip_bfloat16* h1 = y + (size_t)N_NODES * HIDDEN;           // 12.8 MB
    Edge* edges     = (Edge*)(h1 + (size_t)N_NODES * HIDDEN);    // 6.4 MB
    int* hist8      = (int*)(edges + N_EDGES);                   // 6.4 MB (32 copies)
    unsigned short* erank = (unsigned short*)(hist8 + N_COPIES * HIST_STRIDE); // 1.6 MB
    int* cnt        = (int*)(erank + N_EDGES);                   // 200 KB
    int* row_ptr    = cnt + 50176;                               // 50001 (pad 50176)
    int* block_sums = row_ptr + 50176;                           // 64 ints

    // CSR build + gemm1 co-run (interleaved 1:4 so MFMA overlaps atomics)
    hipMemsetAsync(hist8, 0, N_COPIES * HIST_STRIDE * sizeof(int), stream);
    hist_gemm1<<<HG_GRID, 256, 0, stream>>>(edst, hist8, erank, x, W1, y);
    scan_partial<<<SCAN_BLOCKS, SCAN_BS, 0, stream>>>(hist8, cnt, block_sums);
    scan_final<<<SCAN_BLOCKS, SCAN_BS, 0, stream>>>(cnt, block_sums, row_ptr);
    scatter_det<<<N_EDGES / 256, 256, 0, stream>>>(esrc, edst, ew, hist8,
                                                   erank, row_ptr, edges);

    // h1 = relu(A @ y + b1)
    spmm1_kernel<<<N_NODES / 8, 256, 0, stream>>>(row_ptr, edges, y, b1, h1);
    // g = h1 @ W2 (8-row W2 amortization; padded g rows)
    gemm2_kernel<<<N_NODES / G2_ROWS, 64, 0, stream>>>(h1, W2, g);
    // out = A @ g + b2
    spmm2_kernel<<<N_NODES / 8, 256, 0, stream>>>(row_ptr, edges, g, b2, out);
}

// Round 7
// 215.219 us; speedup vs baseline: 1.0750x; 1.0618x over previous
//
#include <hip/hip_runtime.h>
#include <hip/hip_bf16.h>

#define N_NODES 50000
#define N_EDGES 800000
#define IN_DIM 128
#define HIDDEN 128
#define OUT_DIM 40
#define G_STRIDE 64                                       // padded g row (128B line)

#define SCAN_BS 1024
#define SCAN_BLOCKS ((N_NODES + SCAN_BS - 1) / SCAN_BS)   // 49

#define N_COPIES 8                                        // hist copies (32 was null)
#define HIST_STRIDE 50176                                 // line-aligned copy stride

#define HIST_BLOCKS 3128                                  // covers 800768 slots (guarded)
#define G1_BLOCKS ((N_NODES + 63) / 64)                   // 782
#define HG_GRID 3910                                      // 782 gemm1 (bid%5==4) + 3128 hist

struct __align__(8) Edge { int s; float w; };

typedef __attribute__((ext_vector_type(8))) short bf16x8;   // MFMA A/B frag (4 VGPR)
typedef __attribute__((ext_vector_type(4))) float f32x4;    // MFMA C/D frag
typedef __attribute__((ext_vector_type(8))) unsigned short u16x8;
typedef __attribute__((ext_vector_type(4))) unsigned short u16x4;

// fp32 -> bf16 bits with round-to-nearest-even
__device__ __forceinline__ unsigned f32_to_bf16_bits(float f) {
    unsigned u = __float_as_uint(f);
    return (u + 0x7FFFu + ((u >> 16) & 1u)) >> 16;
}
// bf16 bits -> fp32
__device__ __forceinline__ float b2f(unsigned short u) {
    return __uint_as_float(((unsigned)u) << 16);
}

// ---- 1) fused hist + gemm1, INTERLEAVED 1:4 (atomic pass is a measured
// ~44us floor: copies 8 vs 32 and XCD alignment both null) ------------------
__global__ __launch_bounds__(256) void hist_gemm1(const int* __restrict__ dst,
                                                  int* __restrict__ hist8,
                                                  unsigned short* __restrict__ erank,
                                                  const float* __restrict__ x,
                                                  const float* __restrict__ W1,
                                                  __hip_bfloat16* __restrict__ y)
{
    __shared__ bf16x8 w1s[2048];                  // 32 KB (gemm1 blocks only)
    int bid = blockIdx.x;

    if ((bid % 5) != 4) {
        // -------- hist path --------
        int hb = bid - bid / 5;                   // 0..3127
        int i = hb * 256 + threadIdx.x;
        if (i < N_EDGES) {
            int copy = bid & (N_COPIES - 1);
            erank[i] = (unsigned short)atomicAdd(&hist8[copy * HIST_STRIDE + dst[i]], 1);
        }
        return;
    }

    // -------- gemm1 path: y = x @ W1 (v_mfma_f32_16x16x32_bf16) --------
    int gb = bid / 5;                             // 0..781
    int t = threadIdx.x;
    for (int f = t; f < 2048; f += 256) {         // 8 frags per thread
        int lane = f & 63;
        int nt = (f >> 6) & 7;
        int ks = f >> 9;
        int m = lane & 15, quad = lane >> 4;
        bf16x8 frag;
        #pragma unroll
        for (int j = 0; j < 8; ++j) {
            int k = ks * 32 + quad * 8 + j;
            frag[j] = (short)f32_to_bf16_bits(W1[k * HIDDEN + nt * 16 + m]);
        }
        w1s[f] = frag;
    }
    __syncthreads();

    int wv = t >> 6;
    int lane = t & 63;
    int m = lane & 15, quad = lane >> 4;
    int row0 = gb * 64 + wv * 16;
    int arow = row0 + m;
    if (arow >= N_NODES) arow = N_NODES - 1;      // clamp loads; stores guarded

    bf16x8 afrag[4];
    #pragma unroll
    for (int ks = 0; ks < 4; ++ks) {
        const float4* xp = (const float4*)(x + (long long)arow * IN_DIM + ks * 32 + quad * 8);
        float4 a0 = xp[0], a1 = xp[1];
        afrag[ks][0] = (short)f32_to_bf16_bits(a0.x);
        afrag[ks][1] = (short)f32_to_bf16_bits(a0.y);
        afrag[ks][2] = (short)f32_to_bf16_bits(a0.z);
        afrag[ks][3] = (short)f32_to_bf16_bits(a0.w);
        afrag[ks][4] = (short)f32_to_bf16_bits(a1.x);
        afrag[ks][5] = (short)f32_to_bf16_bits(a1.y);
        afrag[ks][6] = (short)f32_to_bf16_bits(a1.z);
        afrag[ks][7] = (short)f32_to_bf16_bits(a1.w);
    }

    f32x4 acc[8];
    #pragma unroll
    for (int nt = 0; nt < 8; ++nt) acc[nt] = (f32x4){0.f, 0.f, 0.f, 0.f};

    #pragma unroll
    for (int ks = 0; ks < 4; ++ks) {
        #pragma unroll
        for (int nt = 0; nt < 8; ++nt) {
            bf16x8 bfrag = w1s[(ks * 8 + nt) * 64 + lane];
            acc[nt] = __builtin_amdgcn_mfma_f32_16x16x32_bf16(afrag[ks], bfrag, acc[nt], 0, 0, 0);
        }
    }

    #pragma unroll
    for (int nt = 0; nt < 8; ++nt) {
        #pragma unroll
        for (int r = 0; r < 4; ++r) {
            int rrow = row0 + quad * 4 + r;
            if (rrow < N_NODES)
                y[(long long)rrow * HIDDEN + nt * 16 + m] = __float2bfloat16(acc[nt][r]);
        }
    }
}

// ---- 2a) convert 8 copies -> per-copy exclusive offsets (in place) -------
__global__ __launch_bounds__(SCAN_BS) void scan_partial(int* __restrict__ hist8,
                                                        int* __restrict__ cnt,
                                                        int* __restrict__ block_sums)
{
    __shared__ int red[SCAN_BS / 64];
    int i = blockIdx.x * SCAN_BS + threadIdx.x;
    int total = 0;
    if (i < N_NODES) {
        int off = 0;
        #pragma unroll
        for (int c = 0; c < N_COPIES; ++c) {
            int h = hist8[c * HIST_STRIDE + i];
            hist8[c * HIST_STRIDE + i] = off;     // exclusive prefix over copies
            off += h;
        }
        total = off;
        cnt[i] = total;
    }
    int s = total;
    for (int off = 32; off > 0; off >>= 1) s += __shfl_down(s, off, 64);
    int wave = threadIdx.x >> 6, lane = threadIdx.x & 63;
    if (lane == 0) red[wave] = s;
    __syncthreads();
    if (threadIdx.x == 0) {
        int tt = 0;
        #pragma unroll
        for (int wv = 0; wv < SCAN_BS / 64; ++wv) tt += red[wv];
        block_sums[blockIdx.x] = tt;
    }
}

// ---- 2b) block-local exclusive scan; PARALLEL prefix over block_sums -----
__global__ __launch_bounds__(SCAN_BS) void scan_final(const int* __restrict__ cnt,
                                                      const int* __restrict__ block_sums,
                                                      int* __restrict__ row_ptr)
{
    __shared__ int tmp[SCAN_BS];
    __shared__ int blk_off;
    int t = threadIdx.x;
    int i = blockIdx.x * SCAN_BS + t;
    if (t < 64) {                                  // SCAN_BLOCKS=49 <= 64 lanes
        int v2 = (t < (int)blockIdx.x) ? block_sums[t] : 0;
        for (int off = 32; off > 0; off >>= 1) v2 += __shfl_down(v2, off, 64);
        if (t == 0) {
            blk_off = v2;
            if (blockIdx.x == 0) row_ptr[N_NODES] = N_EDGES;
        }
    }
    int v = (i < N_NODES) ? cnt[i] : 0;
    tmp[t] = v;
    __syncthreads();
    for (int off = 1; off < SCAN_BS; off <<= 1) {
        int u = (t >= off) ? tmp[t - off] : 0;
        __syncthreads();
        tmp[t] += u;
        __syncthreads();
    }
    if (i < N_NODES) row_ptr[i] = tmp[t] - v + blk_off;
}

// ---- 3) scatter_det: SINGLE-PASS deterministic placement, NO atomics -----
__global__ __launch_bounds__(256) void scatter_det(const int* __restrict__ src,
                                                   const int* __restrict__ dst,
                                                   const float* __restrict__ w,
                                                   const int* __restrict__ hist8,
                                                   const unsigned short* __restrict__ erank,
                                                   const int* __restrict__ row_ptr,
                                                   Edge* __restrict__ edges)
{
    int i = blockIdx.x * 256 + threadIdx.x;       // grid exact: 3125*256
    int d = dst[i];
    int hb = i >> 8;
    int hbid = hb + (hb >> 2);                    // inverse of hb = bid - bid/5
    int copy = hbid & (N_COPIES - 1);             // == hist's bid&7
    int pos = row_ptr[d] + hist8[copy * HIST_STRIDE + d] + (int)erank[i];
    Edge ed; ed.s = src[i]; ed.w = w[i];
    edges[pos] = ed;
}

// ---- 4) spmm1: h1 = relu(A @ y + b1). 16-LANE GROUPS, 16B/lane: each wave
// holds 4 independent nodes; per-group 8-deep chains -> up to 32 row-gathers
// in flight per wave, exec-masked per group (no lockstep-min drain) --------
__global__ __launch_bounds__(256) void spmm1_kernel(const int* __restrict__ row_ptr,
                                                    const Edge* __restrict__ edges,
                                                    const __hip_bfloat16* __restrict__ y,
                                                    const float* __restrict__ b1,
                                                    __hip_bfloat16* __restrict__ h1)
{
    int wv = threadIdx.x >> 6;
    int lane = threadIdx.x & 63;
    int grp = lane >> 4;                          // 0..3
    int sub = lane & 15;                          // 0..15
    int node = blockIdx.x * 16 + wv * 4 + grp;    // grid exact: 3125*16 = 50000
    int j = row_ptr[node];
    int e = row_ptr[node + 1];

    float acc[8];
    #pragma unroll
    for (int k = 0; k < 8; ++k) acc[k] = 0.f;

    for (; j + 7 < e; j += 8) {
        Edge ed[8];
        #pragma unroll
        for (int u = 0; u < 8; ++u) ed[u] = edges[j + u];
        u16x8 v[8];
        #pragma unroll
        for (int u = 0; u < 8; ++u)
            v[u] = *(const u16x8*)(y + ((long long)ed[u].s << 7) + (sub << 3));
        #pragma unroll
        for (int u = 0; u < 8; ++u) {
            #pragma unroll
            for (int k = 0; k < 8; ++k)
                acc[k] = fmaf(ed[u].w, b2f(v[u][k]), acc[k]);
        }
    }
    for (; j + 3 < e; j += 4) {
        Edge ed[4];
        #pragma unroll
        for (int u = 0; u < 4; ++u) ed[u] = edges[j + u];
        u16x8 v[4];
        #pragma unroll
        for (int u = 0; u < 4; ++u)
            v[u] = *(const u16x8*)(y + ((long long)ed[u].s << 7) + (sub << 3));
        #pragma unroll
        for (int u = 0; u < 4; ++u) {
            #pragma unroll
            for (int k = 0; k < 8; ++k)
                acc[k] = fmaf(ed[u].w, b2f(v[u][k]), acc[k]);
        }
    }
    for (; j < e; ++j) {
        Edge ed0 = edges[j];
        u16x8 v0 = *(const u16x8*)(y + ((long long)ed0.s << 7) + (sub << 3));
        #pragma unroll
        for (int k = 0; k < 8; ++k)
            acc[k] = fmaf(ed0.w, b2f(v0[k]), acc[k]);
    }

    float4 bA = *(const float4*)(b1 + (sub << 3));
    float4 bB = *(const float4*)(b1 + (sub << 3) + 4);
    u16x8 hv;
    hv[0] = (unsigned short)f32_to_bf16_bits(fmaxf(acc[0] + bA.x, 0.f));
    hv[1] = (unsigned short)f32_to_bf16_bits(fmaxf(acc[1] + bA.y, 0.f));
    hv[2] = (unsigned short)f32_to_bf16_bits(fmaxf(acc[2] + bA.z, 0.f));
    hv[3] = (unsigned short)f32_to_bf16_bits(fmaxf(acc[3] + bA.w, 0.f));
    hv[4] = (unsigned short)f32_to_bf16_bits(fmaxf(acc[4] + bB.x, 0.f));
    hv[5] = (unsigned short)f32_to_bf16_bits(fmaxf(acc[5] + bB.y, 0.f));
    hv[6] = (unsigned short)f32_to_bf16_bits(fmaxf(acc[6] + bB.z, 0.f));
    hv[7] = (unsigned short)f32_to_bf16_bits(fmaxf(acc[7] + bB.w, 0.f));
    *(u16x8*)(h1 + ((long long)node << 7) + (sub << 3)) = hv;
}

// ---- 5) gemm2: g = h1 @ W2; 8 rows/block amortize the W2 pass. Pad cols
// 40..63 with zeros so every g row is a complete 128B line -----------------
#define G2_ROWS 8
__global__ __launch_bounds__(64) void gemm2_kernel(const __hip_bfloat16* __restrict__ h1,
                                                   const float* __restrict__ W2,
                                                   __hip_bfloat16* __restrict__ g)
{
    __shared__ float xs[G2_ROWS][HIDDEN];
    int row0 = blockIdx.x * G2_ROWS;
    int t = threadIdx.x;
    #pragma unroll
    for (int r = 0; r < G2_ROWS; ++r) {
        xs[r][t]      = __bfloat162float(h1[(long long)(row0 + r) * HIDDEN + t]);
        xs[r][t + 64] = __bfloat162float(h1[(long long)(row0 + r) * HIDDEN + t + 64]);
    }
    __syncthreads();
    if (t >= OUT_DIM) {
        __hip_bfloat16 z = __float2bfloat16(0.f);
        #pragma unroll
        for (int r = 0; r < G2_ROWS; ++r)
            g[((row0 + r) << 6) + t] = z;          // zero the pad cols 40..63
        return;
    }
    float acc[G2_ROWS];
    #pragma unroll
    for (int r = 0; r < G2_ROWS; ++r) acc[r] = 0.f;
    #pragma unroll 4
    for (int k = 0; k < HIDDEN; ++k) {
        float wv = W2[k * OUT_DIM + t];
        #pragma unroll
        for (int r = 0; r < G2_ROWS; ++r)
            acc[r] = fmaf(xs[r][k], wv, acc[r]);
    }
    #pragma unroll
    for (int r = 0; r < G2_ROWS; ++r)
        g[((row0 + r) << 6) + t] = __float2bfloat16(acc[r]);   // padded row
}

// ---- 6) spmm2: out = A @ g + b2. 16-LANE GROUPS, 8B/lane: one group read
// = exactly the one 128B g line (halves per-edge fabric traffic); 4 nodes
// per wave, per-group 8-deep chains ----------------------------------------
__global__ __launch_bounds__(256) void spmm2_kernel(const int* __restrict__ row_ptr,
                                                    const Edge* __restrict__ edges,
                                                    const __hip_bfloat16* __restrict__ g,
                                                    const float* __restrict__ b2,
                                                    float* __restrict__ out)
{
    int wv = threadIdx.x >> 6;
    int lane = threadIdx.x & 63;
    int grp = lane >> 4;                          // 0..3
    int sub = lane & 15;                          // 0..15
    int node = blockIdx.x * 16 + wv * 4 + grp;    // grid exact: 3125*16 = 50000
    int j = row_ptr[node];
    int e = row_ptr[node + 1];

    float acc[4];
    #pragma unroll
    for (int k = 0; k < 4; ++k) acc[k] = 0.f;

    for (; j + 7 < e; j += 8) {
        Edge ed[8];
        #pragma unroll
        for (int u = 0; u < 8; ++u) ed[u] = edges[j + u];
        u16x4 v[8];
        #pragma unroll
        for (int u = 0; u < 8; ++u)
            v[u] = *(const u16x4*)(g + ((long long)ed[u].s << 6) + (sub << 2));
        #pragma unroll
        for (int u = 0; u < 8; ++u) {
            #pragma unroll
            for (int k = 0; k < 4; ++k)
                acc[k] = fmaf(ed[u].w, b2f(v[u][k]), acc[k]);
        }
    }
    for (; j + 3 < e; j += 4) {
        Edge ed[4];
        #pragma unroll
        for (int u = 0; u < 4; ++u) ed[u] = edges[j + u];
        u16x4 v[4];
        #pragma unroll
        for (int u = 0; u < 4; ++u)
            v[u] = *(const u16x4*)(g + ((long long)ed[u].s << 6) + (sub << 2));
        #pragma unroll
        for (int u = 0; u < 4; ++u) {
            #pragma unroll
            for (int k = 0; k < 4; ++k)
                acc[k] = fmaf(ed[u].w, b2f(v[u][k]), acc[k]);
        }
    }
    for (; j < e; ++j) {
        Edge ed0 = edges[j];
        u16x4 v0 = *(const u16x4*)(g + ((long long)ed0.s << 6) + (sub << 2));
        #pragma unroll
        for (int k = 0; k < 4; ++k)
            acc[k] = fmaf(ed0.w, b2f(v0[k]), acc[k]);
    }

    if (sub < 10) {                               // cols 4*sub..4*sub+3 < 40
        float4 bb = *(const float4*)(b2 + (sub << 2));
        float4 o;
        o.x = acc[0] + bb.x;
        o.y = acc[1] + bb.y;
        o.z = acc[2] + bb.z;
        o.w = acc[3] + bb.w;
        *(float4*)(out + (long long)node * OUT_DIM + (sub << 2)) = o;
    }
}

extern "C" void kernel_launch(void* const* d_in, const int* in_sizes, int n_in,
                              void* d_out, int out_size, void* d_ws, size_t ws_size,
                              hipStream_t stream)
{
    const float* x    = (const float*)d_in[0];
    const int*   esrc = (const int*)  d_in[1];
    const int*   edst = (const int*)  d_in[2];
    const float* ew   = (const float*)d_in[3];
    const float* W1   = (const float*)d_in[4];
    const float* b1   = (const float*)d_in[5];
    const float* W2   = (const float*)d_in[6];
    const float* b2   = (const float*)d_in[7];
    float* out = (float*)d_out;

    // workspace layout (~36 MB); g aliases y (y is dead after spmm1)
    __hip_bfloat16* y  = (__hip_bfloat16*)d_ws;                  // 12.8 MB
    __hip_bfloat16* g  = y;                                      // 6.4 MB (aliased)
    __hip_bfloat16* h1 = y + (size_t)N_NODES * HIDDEN;           // 12.8 MB
    Edge* edges     = (Edge*)(h1 + (size_t)N_NODES * HIDDEN);    // 6.4 MB
    int* hist8      = (int*)(edges + N_EDGES);                   // 1.6 MB (8 copies)
    unsigned short* erank = (unsigned short*)(hist8 + N_COPIES * HIST_STRIDE); // 1.6 MB
    int* cnt        = (int*)(erank + N_EDGES);                   // 200 KB
    int* row_ptr    = cnt + 50176;                               // 50001 (pad 50176)
    int* block_sums = row_ptr + 50176;                           // 64 ints

    // CSR build + gemm1 co-run (interleaved 1:4 so MFMA overlaps atomics)
    hipMemsetAsync(hist8, 0, N_COPIES * HIST_STRIDE * sizeof(int), stream);
    hist_gemm1<<<HG_GRID, 256, 0, stream>>>(edst, hist8, erank, x, W1, y);
    scan_partial<<<SCAN_BLOCKS, SCAN_BS, 0, stream>>>(hist8, cnt, block_sums);
    scan_final<<<SCAN_BLOCKS, SCAN_BS, 0, stream>>>(cnt, block_sums, row_ptr);
    scatter_det<<<N_EDGES / 256, 256, 0, stream>>>(esrc, edst, ew, hist8,
                                                   erank, row_ptr, edges);

    // h1 = relu(A @ y + b1)
    spmm1_kernel<<<N_NODES / 16, 256, 0, stream>>>(row_ptr, edges, y, b1, h1);
    // g = h1 @ W2 (8-row W2 amortization; padded+zero-filled g rows)
    gemm2_kernel<<<N_NODES / G2_ROWS, 64, 0, stream>>>(h1, W2, g);
    // out = A @ g + b2
    spmm2_kernel<<<N_NODES / 16, 256, 0, stream>>>(row_ptr, edges, g, b2, out);
}